// Round 13
// baseline (3505.576 us; speedup 1.0000x reference)
//
#include <hip/hip_runtime.h>

// ---------------------------------------------------------------------------
// GPT forward (B=4, T=1024, D=1024, NH=16, DH=64, NL=8, FF=4096, E=512)
// bf16-MFMA GEMMs (fp32 accum), fp32 residual stream, flash attention.
// ---------------------------------------------------------------------------

typedef __attribute__((ext_vector_type(4))) float f32x4;
typedef __attribute__((ext_vector_type(8))) short s16x8;   // 8 bf16 in 4 VGPRs

static __device__ __forceinline__ unsigned short f2b(float f) {
  unsigned int x = __builtin_bit_cast(unsigned int, f);
  x += 0x7fffu + ((x >> 16) & 1u);          // RNE
  return (unsigned short)(x >> 16);
}

static __device__ __forceinline__ void gload_lds16(const unsigned short* g, unsigned short* l) {
  __builtin_amdgcn_global_load_lds((const __attribute__((address_space(1))) void*)g,
                                   (__attribute__((address_space(3))) void*)l, 16, 0, 0);
}

// ---------------------------------------------------------------------------
// GEMM: C[M,N] = A[M,K](bf16) @ Bt[N,K](bf16)^T + bias (+resid) (+gelu)
// 128x128 tile, BK=64, 4 waves, 2-phase double-buffered LDS via global_load_lds.
// EPI: 0 = bf16 out + bias; 1 = bf16 out + bias + exact GELU;
//      2 = f32 out + bias + resid; 3 = f32 out + bias.
// blockIdx.z selects {B,bias,out} set (used to fuse Q,K,V into one launch).
// T1 XCD swizzle on the (x,y) plane: requires gridDim.x*gridDim.y % 8 == 0
// (all call sites: 256 / 1024 / 128 blocks per z-plane).
// NOTE (desk-analysis r6): [row][64] bf16 LDS rows are 128 B -> fragment
// ds_read_b128 has 16-way bank aliasing per 16-lane group. Deliberately NOT
// swizzled: T2 is measured-null on 2-phase structures (regime gate, m228d/
// m230); revisit only with the 8-phase port.
// ---------------------------------------------------------------------------
#define BM 128
#define BN 128
#define BKK 64

template <int EPI>
__global__ __launch_bounds__(256, 2) void gemm_kernel(
    const unsigned short* __restrict__ A,
    const unsigned short* B0, const unsigned short* B1, const unsigned short* B2,
    const float* bias0, const float* bias1, const float* bias2,
    const float* resid,                       // aliases out for EPI==2 (no restrict!)
    void* o0, void* o1, void* o2,
    int M, int N, int K)
{
  const unsigned short* Bp = B0; const float* bias = bias0; void* outp = o0;
  if (blockIdx.z == 1) { Bp = B1; bias = bias1; outp = o1; }
  else if (blockIdx.z == 2) { Bp = B2; bias = bias2; outp = o2; }

  __shared__ unsigned short As[2][BM * BKK];   // 16 KB each
  __shared__ unsigned short Bs[2][BN * BKK];   // total LDS = 64 KB

  // XCD-aware bijective swizzle (nwg % 8 == 0 at every call site):
  // hardware round-robins dispatch id over 8 XCDs; remap so one XCD owns a
  // contiguous run of tile ids (consecutive tiles share the A row-panel in L2).
  const int nwg = gridDim.x * gridDim.y;
  const int bid = blockIdx.y * gridDim.x + blockIdx.x;
  const int cpx = nwg >> 3;
  const int tl  = (bid & 7) * cpx + (bid >> 3);
  const int bx  = tl % gridDim.x, by = tl / gridDim.x;

  const int tid = threadIdx.x, l = tid & 63, w = tid >> 6;
  const int row0 = by * BM, col0 = bx * BN;
  const int srow = w * 8 + (l >> 3);          // staging row within 32-row pass
  const int scol = (l & 7) * 8;               // staging col (bf16 elems)
  const unsigned short* ga = A  + (size_t)(row0 + srow) * K + scol;
  const unsigned short* gb = Bp + (size_t)(col0 + srow) * K + scol;

  const int nk = K / BKK;
  const int wr = (w >> 1) * 64, wc = (w & 1) * 64;
  const int lr = l & 15, lg8 = (l >> 4) * 8;

  f32x4 acc[4][4];
#pragma unroll
  for (int m = 0; m < 4; ++m)
#pragma unroll
    for (int n = 0; n < 4; ++n) acc[m][n] = (f32x4){0.f, 0.f, 0.f, 0.f};

  // prologue: stage k-tile 0 into buf 0
#pragma unroll
  for (int p = 0; p < 4; ++p) {
    gload_lds16(ga + (size_t)p * 32 * K, &As[0][(w * 8 + p * 32) * BKK]);
    gload_lds16(gb + (size_t)p * 32 * K, &Bs[0][(w * 8 + p * 32) * BKK]);
  }
  __syncthreads();   // implies s_waitcnt vmcnt(0) before s_barrier

  int buf = 0;
  for (int kt = 0; kt < nk; ++kt) {
    if (kt + 1 < nk) {
      const unsigned short* ga2 = ga + (size_t)(kt + 1) * BKK;
      const unsigned short* gb2 = gb + (size_t)(kt + 1) * BKK;
#pragma unroll
      for (int p = 0; p < 4; ++p) {
        gload_lds16(ga2 + (size_t)p * 32 * K, &As[buf ^ 1][(w * 8 + p * 32) * BKK]);
        gload_lds16(gb2 + (size_t)p * 32 * K, &Bs[buf ^ 1][(w * 8 + p * 32) * BKK]);
      }
    }
#pragma unroll
    for (int kk = 0; kk < BKK; kk += 32) {
      s16x8 af[4], bfr[4];
#pragma unroll
      for (int m = 0; m < 4; ++m)
        af[m] = *(const s16x8*)&As[buf][(wr + m * 16 + lr) * BKK + kk + lg8];
#pragma unroll
      for (int n = 0; n < 4; ++n)
        bfr[n] = *(const s16x8*)&Bs[buf][(wc + n * 16 + lr) * BKK + kk + lg8];
#pragma unroll
      for (int m = 0; m < 4; ++m)
#pragma unroll
        for (int n = 0; n < 4; ++n)
          acc[m][n] = __builtin_amdgcn_mfma_f32_16x16x32_bf16(af[m], bfr[n], acc[m][n], 0, 0, 0);
    }
    __syncthreads();
    buf ^= 1;
  }

  // epilogue: C row = (l>>4)*4+i within frag, col = l&15  [measured m89/m91]
#pragma unroll
  for (int m = 0; m < 4; ++m) {
    const int r0 = row0 + wr + m * 16 + (l >> 4) * 4;
#pragma unroll
    for (int n = 0; n < 4; ++n) {
      const int c = col0 + wc + n * 16 + lr;
      const float bz = bias[c];
#pragma unroll
      for (int i = 0; i < 4; ++i) {
        float vv = acc[m][n][i] + bz;
        if (EPI == 1) vv = 0.5f * vv * (1.0f + erff(vv * 0.70710678118654752f));
        const size_t idx = (size_t)(r0 + i) * N + c;
        if (EPI == 2) vv += resid[idx];
        if (EPI == 0 || EPI == 1) ((unsigned short*)outp)[idx] = f2b(vv);
        else                      ((float*)outp)[idx] = vv;
      }
    }
  }
}

// ---------------------------------------------------------------------------
// LayerNorm over D=1024: fp32 in -> bf16 out.  One block per row.
// ---------------------------------------------------------------------------
__global__ __launch_bounds__(256) void ln_kernel(const float* __restrict__ x,
                                                 const float* __restrict__ s,
                                                 const float* __restrict__ b,
                                                 unsigned short* __restrict__ out)
{
  const int row = blockIdx.x, tid = threadIdx.x;
  const float4 v = ((const float4*)(x + (size_t)row * 1024))[tid];
  float sum = v.x + v.y + v.z + v.w;
  float sq  = v.x * v.x + v.y * v.y + v.z * v.z + v.w * v.w;
#pragma unroll
  for (int m = 1; m < 64; m <<= 1) { sum += __shfl_xor(sum, m); sq += __shfl_xor(sq, m); }
  __shared__ float red[8];
  if ((tid & 63) == 0) { red[tid >> 6] = sum; red[4 + (tid >> 6)] = sq; }
  __syncthreads();
  sum = red[0] + red[1] + red[2] + red[3];
  sq  = red[4] + red[5] + red[6] + red[7];
  const float mean = sum * (1.f / 1024.f);
  const float var  = sq * (1.f / 1024.f) - mean * mean;
  const float rstd = rsqrtf(var + 1e-5f);
  const float4 sc = ((const float4*)s)[tid];
  const float4 bb = ((const float4*)b)[tid];
  ushort4 o;
  o.x = f2b((v.x - mean) * rstd * sc.x + bb.x);
  o.y = f2b((v.y - mean) * rstd * sc.y + bb.y);
  o.z = f2b((v.z - mean) * rstd * sc.z + bb.z);
  o.w = f2b((v.w - mean) * rstd * sc.w + bb.w);
  ((ushort4*)(out + (size_t)row * 1024))[tid] = o;
}

// ---------------------------------------------------------------------------
// Flash attention, causal. Grid: (qtile=16, b*NH=64). 256 thr = 4 waves,
// each wave owns 16 q rows. K/V tiles 64x64 staged per iteration.
// ---------------------------------------------------------------------------
__global__ __launch_bounds__(256, 2) void attn_kernel(
    const unsigned short* __restrict__ q, const unsigned short* __restrict__ k,
    const unsigned short* __restrict__ v, unsigned short* __restrict__ y)
{
  const int qt = blockIdx.x;
  const int bh = blockIdx.y;
  const int bb = bh >> 4, hh = bh & 15;
  const int tid = threadIdx.x, l = tid & 63, w = tid >> 6;
  const int lr = l & 15, lg = l >> 4, lg8 = lg * 8;

  __shared__ unsigned short Qs[64 * 64];
  __shared__ unsigned short Ks[64 * 64];
  __shared__ unsigned short Vt[64 * 64];      // transposed: Vt[dh][t]
  __shared__ unsigned short Ps[4][16 * 64];   // per-wave P tile

  const size_t rq0 = (size_t)bb * 1024 + (size_t)qt * 64;
  const int ch = hh * 64;

  for (int id = tid; id < 512; id += 256) {
    const int r = id >> 3, c0 = (id & 7) * 8;
    *(s16x8*)&Qs[r * 64 + c0] = *(const s16x8*)&q[(rq0 + r) * 1024 + ch + c0];
  }

  float m_i[4], l_i[4];
  f32x4 accO[4];
#pragma unroll
  for (int i = 0; i < 4; ++i) { m_i[i] = -1e30f; l_i[i] = 0.f; }
#pragma unroll
  for (int n = 0; n < 4; ++n) accO[n] = (f32x4){0.f, 0.f, 0.f, 0.f};

  for (int kt = 0; kt <= qt; ++kt) {
    __syncthreads();    // prior compute done (and Q staged, first iter)
    const size_t rk0 = (size_t)bb * 1024 + (size_t)kt * 64;
    for (int id = tid; id < 512; id += 256) {
      const int r = id >> 3, c0 = (id & 7) * 8;
      *(s16x8*)&Ks[r * 64 + c0] = *(const s16x8*)&k[(rk0 + r) * 1024 + ch + c0];
      s16x8 vv = *(const s16x8*)&v[(rk0 + r) * 1024 + ch + c0];
      const unsigned short* pv = (const unsigned short*)&vv;
#pragma unroll
      for (int j = 0; j < 8; ++j) Vt[(c0 + j) * 64 + r] = pv[j];
    }
    __syncthreads();

    // S = Q K^T : wave rows w*16..w*16+15
    f32x4 s[4];
#pragma unroll
    for (int n = 0; n < 4; ++n) s[n] = (f32x4){0.f, 0.f, 0.f, 0.f};
#pragma unroll
    for (int kk = 0; kk < 64; kk += 32) {
      s16x8 a = *(const s16x8*)&Qs[(w * 16 + lr) * 64 + kk + lg8];
#pragma unroll
      for (int n = 0; n < 4; ++n) {
        s16x8 bfr = *(const s16x8*)&Ks[(n * 16 + lr) * 64 + kk + lg8];
        s[n] = __builtin_amdgcn_mfma_f32_16x16x32_bf16(a, bfr, s[n], 0, 0, 0);
      }
    }

    const int qrow0 = qt * 64 + w * 16 + lg * 4;
    float p[4][4];
#pragma unroll
    for (int i = 0; i < 4; ++i) {
      float mx = -1e30f;
#pragma unroll
      for (int n = 0; n < 4; ++n) {
        float sv = s[n][i] * 0.125f;                       // 1/sqrt(64)
        if (kt == qt && (kt * 64 + n * 16 + lr) > (qrow0 + i)) sv = -1e30f;
        p[n][i] = sv; mx = fmaxf(mx, sv);
      }
      mx = fmaxf(mx, __shfl_xor(mx, 1));
      mx = fmaxf(mx, __shfl_xor(mx, 2));
      mx = fmaxf(mx, __shfl_xor(mx, 4));
      mx = fmaxf(mx, __shfl_xor(mx, 8));
      const float mn = fmaxf(m_i[i], mx);
      const float alpha = __expf(m_i[i] - mn);
      m_i[i] = mn;
      float rs = 0.f;
#pragma unroll
      for (int n = 0; n < 4; ++n) { float pv = __expf(p[n][i] - mn); p[n][i] = pv; rs += pv; }
      rs += __shfl_xor(rs, 1); rs += __shfl_xor(rs, 2);
      rs += __shfl_xor(rs, 4); rs += __shfl_xor(rs, 8);
      l_i[i] = l_i[i] * alpha + rs;
#pragma unroll
      for (int n = 0; n < 4; ++n) accO[n][i] *= alpha;
    }

    // P -> LDS (bf16) so PV can read A-fragments contiguously
#pragma unroll
    for (int i = 0; i < 4; ++i)
#pragma unroll
      for (int n = 0; n < 4; ++n)
        Ps[w][(lg * 4 + i) * 64 + n * 16 + lr] = f2b(p[n][i]);

#pragma unroll
    for (int kk = 0; kk < 64; kk += 32) {
      s16x8 pa = *(const s16x8*)&Ps[w][lr * 64 + kk + lg8];
#pragma unroll
      for (int n = 0; n < 4; ++n) {
        s16x8 vb = *(const s16x8*)&Vt[(n * 16 + lr) * 64 + kk + lg8];
        accO[n] = __builtin_amdgcn_mfma_f32_16x16x32_bf16(pa, vb, accO[n], 0, 0, 0);
      }
    }
  }

#pragma unroll
  for (int n = 0; n < 4; ++n)
#pragma unroll
    for (int i = 0; i < 4; ++i) {
      const float o = accO[n][i] / l_i[i];
      y[(rq0 + w * 16 + lg * 4 + i) * 1024 + ch + n * 16 + lr] = f2b(o);
    }
}

// ---------------------------------------------------------------------------
// fp32 [R,C] -> bf16 [C,R] transpose-convert (64x64 tiles via padded LDS).
// ---------------------------------------------------------------------------
static __device__ __forceinline__ void transpose_body(const float* src, unsigned short* dst,
                                                      int R, int C, int br, int bc,
                                                      float (*tile)[65], int tid)
{
  const int r0 = tid >> 4, c4 = (tid & 15) * 4;
#pragma unroll
  for (int p = 0; p < 4; ++p) {
    const int r = p * 16 + r0;
    const float4 vv = *(const float4*)&src[(size_t)(br + r) * C + bc + c4];
    tile[r][c4 + 0] = vv.x; tile[r][c4 + 1] = vv.y;
    tile[r][c4 + 2] = vv.z; tile[r][c4 + 3] = vv.w;
  }
  __syncthreads();
  const int cc0 = tid >> 4, rr4 = (tid & 15) * 4;
#pragma unroll
  for (int p = 0; p < 4; ++p) {
    const int cc = p * 16 + cc0;
    ushort4 o;
    o.x = f2b(tile[rr4 + 0][cc]);
    o.y = f2b(tile[rr4 + 1][cc]);
    o.z = f2b(tile[rr4 + 2][cc]);
    o.w = f2b(tile[rr4 + 3][cc]);
    *(ushort4*)&dst[(size_t)(bc + cc) * R + br + rr4] = o;
  }
}

__global__ __launch_bounds__(256) void convT_kernel(const float* src, unsigned short* dst,
                                                    int R, int C)
{
  __shared__ float tile[64][65];
  transpose_body(src, dst, R, C, blockIdx.y * 64, blockIdx.x * 64, tile, threadIdx.x);
}

// One launch converts+transposes all 6 weight matrices of a layer. 3072 blocks.
__global__ __launch_bounds__(256) void conv_layer_kernel(
    const float* Wq, const float* Wk, const float* Wv, const float* Wp,
    const float* W1, const float* W2,
    unsigned short* wqt, unsigned short* wkt, unsigned short* wvt, unsigned short* wpt,
    unsigned short* w1t, unsigned short* w2t)
{
  __shared__ float tile[64][65];
  const int bid = blockIdx.x;
  const float* src; unsigned short* dst; int R, C, t;
  if (bid < 1024) {
    const int m = bid >> 8; t = bid & 255; R = 1024; C = 1024;
    src = (m == 0) ? Wq : (m == 1) ? Wk : (m == 2) ? Wv : Wp;
    dst = (m == 0) ? wqt : (m == 1) ? wkt : (m == 2) ? wvt : wpt;
  } else if (bid < 2048) { t = bid - 1024; R = 1024; C = 4096; src = W1; dst = w1t; }
  else                   { t = bid - 2048; R = 4096; C = 1024; src = W2; dst = w2t; }
  const int tX = C >> 6;
  const int bx = t % tX, by = t / tX;
  transpose_body(src, dst, R, C, by * 64, bx * 64, tile, threadIdx.x);
}

// ---------------------------------------------------------------------------
// Embedding: h[m, :512] = shift(lcd) @ W_embed ; h[m, 512:] = action @ W_act ;
// h += pos_emb.  16 rows per block, fp32.
// ---------------------------------------------------------------------------
__global__ __launch_bounds__(256) void embed_kernel(
    const float* __restrict__ lcd, const float* __restrict__ action,
    const float* __restrict__ pos, const float* __restrict__ Wemb,
    const float* __restrict__ Wact, float* __restrict__ h)
{
  __shared__ float xs[16][512];
  __shared__ float as_[16][8];
  const int tid = threadIdx.x;
  const int m0 = blockIdx.x * 16;

  for (int idx = tid; idx < 16 * 128; idx += 256) {     // 128 float4 per row
    const int r = idx >> 7, q4 = idx & 127;
    const int m = m0 + r, bb = m >> 10, t = m & 1023;
    float4 vv;
    if (t == 0) vv = make_float4(0.f, 0.f, 0.f, 0.f);
    else vv = *((const float4*)&lcd[((size_t)bb * 1024 + (t - 1)) * 512] + q4);
    *(float4*)&xs[r][q4 * 4] = vv;
  }
  if (tid < 128) {
    const int r = tid >> 3, a = tid & 7;
    as_[r][a] = action[(size_t)(m0 + r) * 8 + a];
  }
  __syncthreads();

  float acc0[16], acc1[16], acc2[16], acc3[16];
#pragma unroll
  for (int r = 0; r < 16; ++r) { acc0[r] = 0.f; acc1[r] = 0.f; acc2[r] = 0.f; acc3[r] = 0.f; }

  for (int e = 0; e < 512; ++e) {
    const float w0 = Wemb[(size_t)e * 512 + tid];
    const float w1 = Wemb[(size_t)e * 512 + tid + 256];
#pragma unroll
    for (int r = 0; r < 16; ++r) {
      const float xv = xs[r][e];
      acc0[r] += xv * w0; acc1[r] += xv * w1;
    }
  }
#pragma unroll
  for (int a = 0; a < 8; ++a) {
    const float w0 = Wact[a * 512 + tid];
    const float w1 = Wact[a * 512 + tid + 256];
#pragma unroll
    for (int r = 0; r < 16; ++r) {
      const float av = as_[r][a];
      acc2[r] += av * w0; acc3[r] += av * w1;
    }
  }
#pragma unroll
  for (int r = 0; r < 16; ++r) {
    const int m = m0 + r, t = m & 1023;
    h[(size_t)m * 1024 + tid]       = acc0[r] + pos[(size_t)t * 1024 + tid];
    h[(size_t)m * 1024 + tid + 256] = acc1[r] + pos[(size_t)t * 1024 + tid + 256];
    h[(size_t)m * 1024 + tid + 512] = acc2[r] + pos[(size_t)t * 1024 + tid + 512];
    h[(size_t)m * 1024 + tid + 768] = acc3[r] + pos[(size_t)t * 1024 + tid + 768];
  }
}

// ---------------------------------------------------------------------------
extern "C" void kernel_launch(void* const* d_in, const int* in_sizes, int n_in,
                              void* d_out, int out_size, void* d_ws, size_t ws_size,
                              hipStream_t stream)
{
  (void)in_sizes; (void)n_in; (void)out_size; (void)ws_size;

  const float* lcd    = (const float*)d_in[0];
  const float* action = (const float*)d_in[1];
  const float* pos    = (const float*)d_in[2];
  const float* Wemb   = (const float*)d_in[3];
  const float* Wact   = (const float*)d_in[4];
  const float* ln1s   = (const float*)d_in[5];
  const float* ln1b   = (const float*)d_in[6];
  const float* Wq     = (const float*)d_in[7];
  const float* bq     = (const float*)d_in[8];
  const float* Wk     = (const float*)d_in[9];
  const float* bk     = (const float*)d_in[10];
  const float* Wv     = (const float*)d_in[11];
  const float* bv     = (const float*)d_in[12];
  const float* Wp     = (const float*)d_in[13];
  const float* bp     = (const float*)d_in[14];
  const float* ln2s   = (const float*)d_in[15];
  const float* ln2b   = (const float*)d_in[16];
  const float* W1     = (const float*)d_in[17];
  const float* b1     = (const float*)d_in[18];
  const float* W2     = (const float*)d_in[19];
  const float* b2     = (const float*)d_in[20];
  const float* lnfs   = (const float*)d_in[21];
  const float* lnfb   = (const float*)d_in[22];
  const float* Wh     = (const float*)d_in[23];
  const float* bhd    = (const float*)d_in[24];

  // workspace layout (bytes); mlpa aliases q..y (all dead when MLP runs)
  constexpr size_t OFF_H    = 0;                         // 16 MB fp32 [4096,1024]
  constexpr size_t OFF_Z    = 16777216;                  // 8 MB bf16  [4096,1024]
  constexpr size_t OFF_Q    = 25165824;
  constexpr size_t OFF_K    = 33554432;
  constexpr size_t OFF_V    = 41943040;
  constexpr size_t OFF_Y    = 50331648;
  constexpr size_t OFF_MLPA = OFF_Q;                     // 32 MB bf16 [4096,4096]
  constexpr size_t OFF_WQT  = 58720256;
  constexpr size_t OFF_WKT  = OFF_WQT + 2097152;
  constexpr size_t OFF_WVT  = OFF_WKT + 2097152;
  constexpr size_t OFF_WPT  = OFF_WVT + 2097152;
  constexpr size_t OFF_W1T  = OFF_WPT + 2097152;         // [4096,1024] bf16
  constexpr size_t OFF_W2T  = OFF_W1T + 8388608;         // [1024,4096] bf16
  constexpr size_t OFF_WHT  = OFF_W2T + 8388608;         // [512,1024]  bf16
  // total = 84,934,656 bytes

  char* ws = (char*)d_ws;
  float* h            = (float*)(ws + OFF_H);
  unsigned short* z   = (unsigned short*)(ws + OFF_Z);
  unsigned short* qb  = (unsigned short*)(ws + OFF_Q);
  unsigned short* kb  = (unsigned short*)(ws + OFF_K);
  unsigned short* vb  = (unsigned short*)(ws + OFF_V);
  unsigned short* yb  = (unsigned short*)(ws + OFF_Y);
  unsigned short* mlpa= (unsigned short*)(ws + OFF_MLPA);
  unsigned short* wqt = (unsigned short*)(ws + OFF_WQT);
  unsigned short* wkt = (unsigned short*)(ws + OFF_WKT);
  unsigned short* wvt = (unsigned short*)(ws + OFF_WVT);
  unsigned short* wpt = (unsigned short*)(ws + OFF_WPT);
  unsigned short* w1t = (unsigned short*)(ws + OFF_W1T);
  unsigned short* w2t = (unsigned short*)(ws + OFF_W2T);
  unsigned short* wht = (unsigned short*)(ws + OFF_WHT);

  embed_kernel<<<256, 256, 0, stream>>>(lcd, action, pos, Wemb, Wact, h);

  for (int ly = 0; ly < 8; ++ly) {
    const size_t oDD = (size_t)ly * 1024 * 1024;
    const size_t oDF = (size_t)ly * 1024 * 4096;
    const size_t oD  = (size_t)ly * 1024;
    const size_t oF  = (size_t)ly * 4096;

    conv_layer_kernel<<<3072, 256, 0, stream>>>(
        Wq + oDD, Wk + oDD, Wv + oDD, Wp + oDD, W1 + oDF, W2 + oDF,
        wqt, wkt, wvt, wpt, w1t, w2t);

    ln_kernel<<<4096, 256, 0, stream>>>(h, ln1s + oD, ln1b + oD, z);

    gemm_kernel<0><<<dim3(8, 32, 3), 256, 0, stream>>>(
        z, wqt, wkt, wvt, bq + oD, bk + oD, bv + oD, nullptr,
        qb, kb, vb, 4096, 1024, 1024);

    attn_kernel<<<dim3(16, 64), 256, 0, stream>>>(qb, kb, vb, yb);

    gemm_kernel<2><<<dim3(8, 32, 1), 256, 0, stream>>>(
        yb, wpt, wpt, wpt, bp + oD, bp + oD, bp + oD, h,
        h, h, h, 4096, 1024, 1024);

    ln_kernel<<<4096, 256, 0, stream>>>(h, ln2s + oD, ln2b + oD, z);

    gemm_kernel<1><<<dim3(32, 32, 1), 256, 0, stream>>>(
        z, w1t, w1t, w1t, b1 + oF, b1 + oF, b1 + oF, nullptr,
        mlpa, mlpa, mlpa, 4096, 4096, 1024);

    gemm_kernel<2><<<dim3(8, 32, 1), 256, 0, stream>>>(
        mlpa, w2t, w2t, w2t, b2 + oD, b2 + oD, b2 + oD, h,
        h, h, h, 4096, 1024, 4096);
  }

  ln_kernel<<<4096, 256, 0, stream>>>(h, lnfs, lnfb, z);
  convT_kernel<<<dim3(8, 16), 256, 0, stream>>>(Wh, wht, 1024, 512);
  gemm_kernel<3><<<dim3(4, 32, 1), 256, 0, stream>>>(
      z, wht, wht, wht, bhd, bhd, bhd, nullptr,
      d_out, d_out, d_out, 4096, 512, 1024);
}